// Round 17
// baseline (83.264 us; speedup 1.0000x reference)
//
#include <hip/hip_runtime.h>

// B=2, T=2048, D_IN=D_OUT=512, H=8, DK=64
constexpr int B_   = 2;
constexpr int T_   = 2048;
constexpr int DIN  = 512;
constexpr int DOUT = 512;
constexpr int H_   = 8;
constexpr int DK_  = 64;

constexpr float LOG2E = 1.44269504088896340736f;

typedef float    f32x16  __attribute__((ext_vector_type(16)));
typedef short    short8v __attribute__((ext_vector_type(8)));
typedef __bf16   bf16x8  __attribute__((ext_vector_type(8)));

__device__ inline f32x16 mfma3216(short8v a, short8v b, f32x16 c) {
    return __builtin_amdgcn_mfma_f32_32x32x16_bf16(
        __builtin_bit_cast(bf16x8, a), __builtin_bit_cast(bf16x8, b), c, 0, 0, 0);
}

__device__ inline unsigned short bf16c(float f) {
    return __builtin_bit_cast(unsigned short, (__bf16)f);
}
__device__ inline unsigned pk2(float lo, float hi) {
    return (unsigned)bf16c(lo) | ((unsigned)bf16c(hi) << 16);
}
// swap: x'[32:63] = y[0:31], y'[0:31] = x[32:63]
__device__ __forceinline__ void pl32swap(unsigned &x, unsigned &y) {
    asm("v_permlane32_swap_b32 %0, %1" : "+v"(x), "+v"(y));
}

// ---------------------------------------------------------------------------
// Epilogue store: MODE 0 f32 [M,N]; 1 bf16 [B,H,T,DK]; 3 K-frag; 4 V-frag.
// ---------------------------------------------------------------------------
template<int MODE>
__device__ __forceinline__ void store_c(unsigned short* __restrict__ outb,
                                        float* __restrict__ outf,
                                        int m, int n, float v)
{
    if constexpr (MODE == 0) {
        outf[(size_t)m * DOUT + n] = v;
    } else {
        const int bb = m >> 11, t = m & (T_ - 1);
        const int hh = n >> 6,  d = n & (DK_ - 1);
        const size_t bh = (size_t)bb * H_ + hh;
        if constexpr (MODE == 1) {
            outb[(bh * T_ + t) * DK_ + d] = bf16c(v);
        } else if constexpr (MODE == 3) {
            // K-frag: [bh][kt][c*2+khi][l31][8]
            const int kt = t >> 5, l31 = t & 31;
            const int c = d >> 4, khi = (d >> 3) & 1, e = d & 7;
            outb[(bh * 64 + kt) * 2048 + (c * 2 + khi) * 256 + l31 * 8 + e] = bf16c(v);
        } else {
            // V-frag: [bh][kt][(kgrp*2+dblk)*2+khi][l31][8]
            const int kt = t >> 5, kgrp = (t >> 4) & 1, khi = (t >> 3) & 1, e = t & 7;
            const int dblk = d >> 5, l31 = d & 31;
            outb[(bh * 64 + kt) * 2048 + ((kgrp * 2 + dblk) * 2 + khi) * 256 + l31 * 8 + e] = bf16c(v);
        }
    }
}

// ---------------------------------------------------------------------------
// MFMA GEMM (r7/r15 structure, generalized BK; weights staged from f32 with
// inline bf16 conversion):  out = A @ bf16(W*wscale)^T + bias*bscale
// BM=128, BN=64/128, BK=32/64, 4 waves. Single LDS buffer, two barriers per
// K-step, reg-prefetch of step kb+1. LDS XOR-swizzle pos ^= (row>>1)&(CPR-1).
// k-chunk visit order (pos = ks*2+hi8, ascending) is identical across BK —
// per-output MFMA sequence unchanged -> bit-identical results.
// Tile coords (m_blk, n_blk) passed in so callers can XCD-swizzle the grid.
// ---------------------------------------------------------------------------
template<int MODE, bool AF32, int BN, int BK>
__device__ inline void gemm_body(
    const void* __restrict__ Av, const float* __restrict__ Bp,
    const float* __restrict__ bias, float bscale, float wscale,
    unsigned short* __restrict__ outb, float* __restrict__ outf,
    int n_blk, int m_blk)
{
    constexpr int CPR  = BK / 8;              // 16B chunks per row
    constexpr int SWM  = CPR - 1;             // swizzle mask
    constexpr int ACPT = 128 * CPR / 256;     // A chunks per thread
    constexpr int BCPT = BN  * CPR / 256;     // B chunks per thread
    constexpr int RB   = BK * 2;              // row bytes in LDS

    __shared__ unsigned short As[128 * BK];
    __shared__ unsigned short Bs[BN * BK];

    const int tid = threadIdx.x;
    const int m0 = m_blk * 128, n0 = n_blk * BN;
    const int lane31 = tid & 31, hi8 = (tid & 63) >> 5;
    const int wv = tid >> 6, wm = wv >> 1, wn = wv & 1;

    short8v areg[ACPT], breg[BCPT];

    auto gload = [&](int kb) {
        const int k0 = kb * BK;
#pragma unroll
        for (int i = 0; i < ACPT; ++i) {
            const int c = tid + i * 256, r = c / CPR, pos = c % CPR;
            if constexpr (AF32) {
                const float* Af = (const float*)Av;
                const float4 f0 = *(const float4*)&Af[(size_t)(m0 + r) * DIN + k0 + pos * 8];
                const float4 f1 = *(const float4*)&Af[(size_t)(m0 + r) * DIN + k0 + pos * 8 + 4];
                union { unsigned w[4]; short8v v; } u;
                u.w[0] = pk2(f0.x, f0.y); u.w[1] = pk2(f0.z, f0.w);
                u.w[2] = pk2(f1.x, f1.y); u.w[3] = pk2(f1.z, f1.w);
                areg[i] = u.v;
            } else {
                const unsigned short* Ab = (const unsigned short*)Av;
                areg[i] = *(const short8v*)&Ab[(size_t)(m0 + r) * DIN + k0 + pos * 8];
            }
        }
#pragma unroll
        for (int i = 0; i < BCPT; ++i) {
            const int c = tid + i * 256, r = c / CPR, pos = c % CPR;
            const float4 f0 = *(const float4*)&Bp[(size_t)(n0 + r) * DIN + k0 + pos * 8];
            const float4 f1 = *(const float4*)&Bp[(size_t)(n0 + r) * DIN + k0 + pos * 8 + 4];
            union { unsigned w[4]; short8v v; } u;
            u.w[0] = pk2(f0.x * wscale, f0.y * wscale);
            u.w[1] = pk2(f0.z * wscale, f0.w * wscale);
            u.w[2] = pk2(f1.x * wscale, f1.y * wscale);
            u.w[3] = pk2(f1.z * wscale, f1.w * wscale);
            breg[i] = u.v;
        }
    };
    auto swrite = [&]() {
#pragma unroll
        for (int i = 0; i < ACPT; ++i) {
            const int c = tid + i * 256, r = c / CPR, pos = c % CPR;
            *(short8v*)((char*)As + r * RB + ((pos ^ ((r >> 1) & SWM)) << 4)) = areg[i];
        }
#pragma unroll
        for (int i = 0; i < BCPT; ++i) {
            const int c = tid + i * 256, r = c / CPR, pos = c % CPR;
            *(short8v*)((char*)Bs + r * RB + ((pos ^ ((r >> 1) & SWM)) << 4)) = breg[i];
        }
    };

    f32x16 acc00 = {}, acc01 = {}, acc10 = {}, acc11 = {};

    constexpr int NKB = 512 / BK;
    gload(0);
    for (int kb = 0; kb < NKB; ++kb) {
        swrite();
        __syncthreads();
        if (kb < NKB - 1) gload(kb + 1);   // prefetch next step during compute
#pragma unroll
        for (int ks = 0; ks < BK / 16; ++ks) {
            const int pos = ks * 2 + hi8;
            short8v a0, a1;
            { const int r = wm * 64 + lane31;
              a0 = *(const short8v*)((char*)As + r * RB + ((pos ^ ((r >> 1) & SWM)) << 4)); }
            { const int r = wm * 64 + 32 + lane31;
              a1 = *(const short8v*)((char*)As + r * RB + ((pos ^ ((r >> 1) & SWM)) << 4)); }
            if constexpr (BN == 64) {
                short8v b0h;
                { const int r = wn * 32 + lane31;
                  b0h = *(const short8v*)((char*)Bs + r * RB + ((pos ^ ((r >> 1) & SWM)) << 4)); }
                acc00 = mfma3216(a0, b0h, acc00);
                acc10 = mfma3216(a1, b0h, acc10);
            } else {
                short8v b0h, b1h;
                { const int r = wn * 64 + lane31;
                  b0h = *(const short8v*)((char*)Bs + r * RB + ((pos ^ ((r >> 1) & SWM)) << 4)); }
                { const int r = wn * 64 + 32 + lane31;
                  b1h = *(const short8v*)((char*)Bs + r * RB + ((pos ^ ((r >> 1) & SWM)) << 4)); }
                acc00 = mfma3216(a0, b0h, acc00);
                acc01 = mfma3216(a0, b1h, acc01);
                acc10 = mfma3216(a1, b0h, acc10);
                acc11 = mfma3216(a1, b1h, acc11);
            }
        }
        __syncthreads();
    }

    // ---- epilogue
    const int nb = n0 + wn * (BN / 2) + lane31;
#pragma unroll
    for (int r = 0; r < 16; ++r) {
        const int row = (r & 3) + 8 * (r >> 2) + 4 * hi8;
        store_c<MODE>(outb, outf, m0 + wm * 64 + row,      nb, acc00[r] + bias[nb] * bscale);
        store_c<MODE>(outb, outf, m0 + wm * 64 + 32 + row, nb, acc10[r] + bias[nb] * bscale);
        if constexpr (BN == 128) {
            store_c<MODE>(outb, outf, m0 + wm * 64 + row,      nb + 32, acc01[r] + bias[nb + 32] * bscale);
            store_c<MODE>(outb, outf, m0 + wm * 64 + 32 + row, nb + 32, acc11[r] + bias[nb + 32] * bscale);
        }
    }
}

// qkv: BK=64 (8 barrier-pairs instead of 16) + XCD-consolidation swizzle:
// linear dispatch puts the 4 blocks sharing an A-panel on 4 different XCDs;
// remap (bijective) so they share one XCD's L2. Pure tile reassignment.
__global__ __launch_bounds__(256) void qkv_gemm(
    const float* __restrict__ q, const float* __restrict__ k, const float* __restrict__ v,
    const float* __restrict__ Wq, const float* __restrict__ Wk, const float* __restrict__ Wv,
    const float* __restrict__ bq, const float* __restrict__ bk, const float* __restrict__ bv,
    unsigned short* __restrict__ Qh, unsigned short* __restrict__ Kf,
    unsigned short* __restrict__ Vf)
{
    const int lin  = blockIdx.x + 4 * blockIdx.y;   // 0..127
    const int xcd  = lin & 7, slot = lin >> 3;      // slot 0..15
    const int bx   = slot & 3;                      // n-tile
    const int by   = xcd + 8 * (slot >> 2);         // m-tile: same-A blocks -> same XCD
    const int z = blockIdx.z;
    if (z == 0)      gemm_body<1, true, 128, 64>(q, Wq, bq, LOG2E, LOG2E, Qh, nullptr, bx, by);
    else if (z == 1) gemm_body<3, true, 128, 64>(k, Wk, bk, 1.0f,  1.0f,  Kf, nullptr, bx, by);
    else             gemm_body<4, true, 128, 64>(v, Wv, bv, 1.0f,  1.0f,  Vf, nullptr, bx, by);
}

__global__ __launch_bounds__(256) void out_gemm(
    const unsigned short* __restrict__ A, const float* __restrict__ Wo,
    const float* __restrict__ bias, float* __restrict__ out)
{
    gemm_body<0, false, 64, 64>(A, Wo, bias, 1.0f, 1.0f, nullptr, out,
                                blockIdx.x, blockIdx.y);
}

// ---------------------------------------------------------------------------
// MFMA two-pass attention — r12/r15/r16 VERBATIM (proven 47.5 µs form).
// 8 waves, 8-way key split, exp2, permlane repack, 4-partial lsum,
// two-stage LDS combine. 1024 blocks of 32 q-rows.
// ---------------------------------------------------------------------------
__global__ __launch_bounds__(512) void attn_kernel(
    const unsigned short* __restrict__ Qh, const unsigned short* __restrict__ Kf,
    const unsigned short* __restrict__ Vf, unsigned short* __restrict__ concat)
{
    __shared__ float lds_l[8][32];
    __shared__ float lds_out[4][32][64];   // 32 KB, two-stage combine

    const int bid = blockIdx.x;
    const int xcd = bid & 7;
    const int j   = bid >> 3;
    const int bh  = 2 * xcd + (j >> 6);
    const int qt  = j & 63;

    const int tid    = threadIdx.x;
    const int w      = tid >> 6;         // 0..7: key octant
    const int l      = tid & 63;
    const int lane31 = l & 31;
    const int hi     = l >> 5;

    const int q0 = qt * 32;
    const unsigned short* Qb = Qh + ((size_t)bh * T_ + q0) * DK_;

    // Q B-fragments: col = lane31 (query), k = d = c*16 + hi*8 + {0..7}
    short8v qf[4];
#pragma unroll
    for (int c = 0; c < 4; ++c)
        qf[c] = *(const short8v*)(Qb + (size_t)lane31 * DK_ + c * 16 + hi * 8);

    // fragment-major bases for this wave's 8 tiles (keys w*256 .. w*256+255)
    const unsigned short* Kw = Kf + ((size_t)bh * 64 + w * 8) * 2048 + hi * 256 + lane31 * 8;
    const unsigned short* Vw = Vf + ((size_t)bh * 64 + w * 8) * 2048 + hi * 256 + lane31 * 8;

    // ---- pass 1: denominators (exp2; 4 partial sums)
    float ls0 = 0.f, ls1 = 0.f, ls2 = 0.f, ls3 = 0.f;
    for (int kt = 0; kt < 8; ++kt) {
        const unsigned short* Kt = Kw + kt * 2048;
        short8v kf[4];
#pragma unroll
        for (int c = 0; c < 4; ++c)
            kf[c] = *(const short8v*)(Kt + c * 512);
        f32x16 acc = {};
        __builtin_amdgcn_s_setprio(1);
#pragma unroll
        for (int c = 0; c < 4; ++c)
            acc = mfma3216(kf[c], qf[c], acc);
        __builtin_amdgcn_s_setprio(0);
#pragma unroll
        for (int r = 0; r < 16; r += 4) {
            ls0 += __builtin_amdgcn_exp2f(acc[r + 0]);
            ls1 += __builtin_amdgcn_exp2f(acc[r + 1]);
            ls2 += __builtin_amdgcn_exp2f(acc[r + 2]);
            ls3 += __builtin_amdgcn_exp2f(acc[r + 3]);
        }
    }
    float lsum = (ls0 + ls1) + (ls2 + ls3);
    lsum += __shfl_xor(lsum, 32);
    if (l < 32) lds_l[w][l] = lsum;
    __syncthreads();
    float ltot = 0.f;
#pragma unroll
    for (int i = 0; i < 8; ++i) ltot += lds_l[i][lane31];
    const float thr = ltot * (1.0f / 2048.0f);   // e > thr  <=>  p > row mean (=1/T)
    const float inv = 1.0f / ltot;

    // ---- pass 2: masked PV (exp2, permlane repack)
    f32x16 o0 = {}, o1 = {};
    for (int kt = 0; kt < 8; ++kt) {
        const unsigned short* Kt = Kw + kt * 2048;
        short8v kf[4];
#pragma unroll
        for (int c = 0; c < 4; ++c)
            kf[c] = *(const short8v*)(Kt + c * 512);
        f32x16 acc = {};
        __builtin_amdgcn_s_setprio(1);
#pragma unroll
        for (int c = 0; c < 4; ++c)
            acc = mfma3216(kf[c], qf[c], acc);
        __builtin_amdgcn_s_setprio(0);

        float p[16];
#pragma unroll
        for (int r = 0; r < 16; ++r) {
            const float e = __builtin_amdgcn_exp2f(acc[r]);
            p[r] = (e > thr) ? e : 0.f;
        }

        // repack S^T -> PV A-frag via permlane32_swap
        short8v pa[2];
#pragma unroll
        for (int h = 0; h < 2; ++h) {
            unsigned a  = pk2(p[8 * h + 0], p[8 * h + 1]);
            unsigned b2 = pk2(p[8 * h + 2], p[8 * h + 3]);
            unsigned c2 = pk2(p[8 * h + 4], p[8 * h + 5]);
            unsigned d2 = pk2(p[8 * h + 6], p[8 * h + 7]);
            pl32swap(a, c2);
            pl32swap(b2, d2);
            union { unsigned w2[4]; short8v v8; } u;
            u.w2[0] = a; u.w2[1] = b2; u.w2[2] = c2; u.w2[3] = d2;
            pa[h] = u.v8;
        }

        const unsigned short* Vt_ = Vw + kt * 2048;
        short8v vf0 = *(const short8v*)(Vt_);
        short8v vf1 = *(const short8v*)(Vt_ + 512);
        short8v vf2 = *(const short8v*)(Vt_ + 1024);
        short8v vf3 = *(const short8v*)(Vt_ + 1536);
        __builtin_amdgcn_s_setprio(1);
        o0 = mfma3216(pa[0], vf0, o0);
        o1 = mfma3216(pa[0], vf1, o1);
        o0 = mfma3216(pa[1], vf2, o0);
        o1 = mfma3216(pa[1], vf3, o1);
        __builtin_amdgcn_s_setprio(0);
    }

    // ---- two-stage combine of 8 key-octants via 4 LDS buffers
    if (w >= 4) {
#pragma unroll
        for (int r = 0; r < 16; ++r) {
            const int row = (r & 3) + 8 * (r >> 2) + 4 * hi;
            lds_out[w - 4][row][lane31]      = o0[r];
            lds_out[w - 4][row][32 + lane31] = o1[r];
        }
    }
    __syncthreads();
    if (w < 4) {
#pragma unroll
        for (int r = 0; r < 16; ++r) {
            const int row = (r & 3) + 8 * (r >> 2) + 4 * hi;
            o0[r] += lds_out[w][row][lane31];
            o1[r] += lds_out[w][row][32 + lane31];
        }
    }
    __syncthreads();
    if (w >= 1 && w < 4) {
#pragma unroll
        for (int r = 0; r < 16; ++r) {
            const int row = (r & 3) + 8 * (r >> 2) + 4 * hi;
            lds_out[w - 1][row][lane31]      = o0[r];
            lds_out[w - 1][row][32 + lane31] = o1[r];
        }
    }
    __syncthreads();
    if (w == 0) {
        const int b = bh >> 3, h = bh & 7;
        unsigned short* Cb = concat + ((size_t)b * T_ + q0) * DOUT + h * DK_;
#pragma unroll
        for (int r = 0; r < 16; ++r) {
            const int row = (r & 3) + 8 * (r >> 2) + 4 * hi;
            const float iv = __shfl(inv, row);
            const float v0 = o0[r] + lds_out[0][row][lane31]
                           + lds_out[1][row][lane31] + lds_out[2][row][lane31];
            const float v1 = o1[r] + lds_out[0][row][32 + lane31]
                           + lds_out[1][row][32 + lane31] + lds_out[2][row][32 + lane31];
            Cb[(size_t)row * DOUT + lane31]      = bf16c(v0 * iv);
            Cb[(size_t)row * DOUT + 32 + lane31] = bf16c(v1 * iv);
        }
    }
}

// ---------------------------------------------------------------------------
extern "C" void kernel_launch(void* const* d_in, const int* in_sizes, int n_in,
                              void* d_out, int out_size, void* d_ws, size_t ws_size,
                              hipStream_t stream)
{
    const float* q  = (const float*)d_in[0];
    const float* k  = (const float*)d_in[1];
    const float* v  = (const float*)d_in[2];
    const float* Wq = (const float*)d_in[3];
    const float* bq = (const float*)d_in[4];
    const float* Wk = (const float*)d_in[5];
    const float* bk = (const float*)d_in[6];
    const float* Wv = (const float*)d_in[7];
    const float* bv = (const float*)d_in[8];
    const float* Wo = (const float*)d_in[9];
    const float* bo = (const float*)d_in[10];
    float* out = (float*)d_out;

    constexpr size_t M2 = 2097152;  // 2M elements
    unsigned short* ws     = (unsigned short*)d_ws;
    unsigned short* Qh     = ws;
    unsigned short* Kf     = ws + 1 * M2;
    unsigned short* Vf     = ws + 2 * M2;
    unsigned short* concat = ws + 3 * M2;

    qkv_gemm<<<dim3(4, 32, 3), 256, 0, stream>>>(q, k, v, Wq, Wk, Wv, bq, bk, bv, Qh, Kf, Vf);
    attn_kernel<<<dim3(1024), 512, 0, stream>>>(Qh, Kf, Vf, concat);
    out_gemm<<<dim3(8, 32), 256, 0, stream>>>(concat, Wo, bo, out);
}

// Round 18
// 78.078 us; speedup vs baseline: 1.0664x; 1.0664x over previous
//
#include <hip/hip_runtime.h>

// B=2, T=2048, D_IN=D_OUT=512, H=8, DK=64
constexpr int B_   = 2;
constexpr int T_   = 2048;
constexpr int DIN  = 512;
constexpr int DOUT = 512;
constexpr int H_   = 8;
constexpr int DK_  = 64;

constexpr float LOG2E = 1.44269504088896340736f;

typedef float    f32x16  __attribute__((ext_vector_type(16)));
typedef short    short8v __attribute__((ext_vector_type(8)));
typedef __bf16   bf16x8  __attribute__((ext_vector_type(8)));

__device__ inline f32x16 mfma3216(short8v a, short8v b, f32x16 c) {
    return __builtin_amdgcn_mfma_f32_32x32x16_bf16(
        __builtin_bit_cast(bf16x8, a), __builtin_bit_cast(bf16x8, b), c, 0, 0, 0);
}

__device__ inline unsigned short bf16c(float f) {
    return __builtin_bit_cast(unsigned short, (__bf16)f);
}
__device__ inline unsigned pk2(float lo, float hi) {
    return (unsigned)bf16c(lo) | ((unsigned)bf16c(hi) << 16);
}
// swap: x'[32:63] = y[0:31], y'[0:31] = x[32:63]
__device__ __forceinline__ void pl32swap(unsigned &x, unsigned &y) {
    asm("v_permlane32_swap_b32 %0, %1" : "+v"(x), "+v"(y));
}

// ---------------------------------------------------------------------------
// Epilogue store: MODE 0 f32 [M,N]; 1 bf16 [B,H,T,DK]; 3 K-frag; 4 V-frag.
// ---------------------------------------------------------------------------
template<int MODE>
__device__ __forceinline__ void store_c(unsigned short* __restrict__ outb,
                                        float* __restrict__ outf,
                                        int m, int n, float v)
{
    if constexpr (MODE == 0) {
        outf[(size_t)m * DOUT + n] = v;
    } else {
        const int bb = m >> 11, t = m & (T_ - 1);
        const int hh = n >> 6,  d = n & (DK_ - 1);
        const size_t bh = (size_t)bb * H_ + hh;
        if constexpr (MODE == 1) {
            outb[(bh * T_ + t) * DK_ + d] = bf16c(v);
        } else if constexpr (MODE == 3) {
            // K-frag: [bh][kt][c*2+khi][l31][8]
            const int kt = t >> 5, l31 = t & 31;
            const int c = d >> 4, khi = (d >> 3) & 1, e = d & 7;
            outb[(bh * 64 + kt) * 2048 + (c * 2 + khi) * 256 + l31 * 8 + e] = bf16c(v);
        } else {
            // V-frag: [bh][kt][(kgrp*2+dblk)*2+khi][l31][8]
            const int kt = t >> 5, kgrp = (t >> 4) & 1, khi = (t >> 3) & 1, e = t & 7;
            const int dblk = d >> 5, l31 = d & 31;
            outb[(bh * 64 + kt) * 2048 + ((kgrp * 2 + dblk) * 2 + khi) * 256 + l31 * 8 + e] = bf16c(v);
        }
    }
}

// ---------------------------------------------------------------------------
// MFMA GEMM (r7/r15 structure, generalized BK; weights staged from f32 with
// inline bf16 conversion):  out = A @ bf16(W*wscale)^T + bias*bscale
// BM=128, BN=64/128, BK=32/64, 4 waves. Single LDS buffer, two barriers per
// K-step, reg-prefetch of step kb+1. LDS XOR-swizzle pos ^= (row>>1)&(CPR-1).
// k-chunk visit order (pos = ks*2+hi8, ascending) is identical across BK —
// per-output MFMA sequence unchanged -> bit-identical results.
// Tile coords (m_blk, n_blk) passed in so callers can XCD-swizzle the grid.
// ---------------------------------------------------------------------------
template<int MODE, bool AF32, int BN, int BK>
__device__ inline void gemm_body(
    const void* __restrict__ Av, const float* __restrict__ Bp,
    const float* __restrict__ bias, float bscale, float wscale,
    unsigned short* __restrict__ outb, float* __restrict__ outf,
    int n_blk, int m_blk)
{
    constexpr int CPR  = BK / 8;              // 16B chunks per row
    constexpr int SWM  = CPR - 1;             // swizzle mask
    constexpr int ACPT = 128 * CPR / 256;     // A chunks per thread
    constexpr int BCPT = BN  * CPR / 256;     // B chunks per thread
    constexpr int RB   = BK * 2;              // row bytes in LDS

    __shared__ unsigned short As[128 * BK];
    __shared__ unsigned short Bs[BN * BK];

    const int tid = threadIdx.x;
    const int m0 = m_blk * 128, n0 = n_blk * BN;
    const int lane31 = tid & 31, hi8 = (tid & 63) >> 5;
    const int wv = tid >> 6, wm = wv >> 1, wn = wv & 1;

    short8v areg[ACPT], breg[BCPT];

    auto gload = [&](int kb) {
        const int k0 = kb * BK;
#pragma unroll
        for (int i = 0; i < ACPT; ++i) {
            const int c = tid + i * 256, r = c / CPR, pos = c % CPR;
            if constexpr (AF32) {
                const float* Af = (const float*)Av;
                const float4 f0 = *(const float4*)&Af[(size_t)(m0 + r) * DIN + k0 + pos * 8];
                const float4 f1 = *(const float4*)&Af[(size_t)(m0 + r) * DIN + k0 + pos * 8 + 4];
                union { unsigned w[4]; short8v v; } u;
                u.w[0] = pk2(f0.x, f0.y); u.w[1] = pk2(f0.z, f0.w);
                u.w[2] = pk2(f1.x, f1.y); u.w[3] = pk2(f1.z, f1.w);
                areg[i] = u.v;
            } else {
                const unsigned short* Ab = (const unsigned short*)Av;
                areg[i] = *(const short8v*)&Ab[(size_t)(m0 + r) * DIN + k0 + pos * 8];
            }
        }
#pragma unroll
        for (int i = 0; i < BCPT; ++i) {
            const int c = tid + i * 256, r = c / CPR, pos = c % CPR;
            const float4 f0 = *(const float4*)&Bp[(size_t)(n0 + r) * DIN + k0 + pos * 8];
            const float4 f1 = *(const float4*)&Bp[(size_t)(n0 + r) * DIN + k0 + pos * 8 + 4];
            union { unsigned w[4]; short8v v; } u;
            u.w[0] = pk2(f0.x * wscale, f0.y * wscale);
            u.w[1] = pk2(f0.z * wscale, f0.w * wscale);
            u.w[2] = pk2(f1.x * wscale, f1.y * wscale);
            u.w[3] = pk2(f1.z * wscale, f1.w * wscale);
            breg[i] = u.v;
        }
    };
    auto swrite = [&]() {
#pragma unroll
        for (int i = 0; i < ACPT; ++i) {
            const int c = tid + i * 256, r = c / CPR, pos = c % CPR;
            *(short8v*)((char*)As + r * RB + ((pos ^ ((r >> 1) & SWM)) << 4)) = areg[i];
        }
#pragma unroll
        for (int i = 0; i < BCPT; ++i) {
            const int c = tid + i * 256, r = c / CPR, pos = c % CPR;
            *(short8v*)((char*)Bs + r * RB + ((pos ^ ((r >> 1) & SWM)) << 4)) = breg[i];
        }
    };

    f32x16 acc00 = {}, acc01 = {}, acc10 = {}, acc11 = {};

    constexpr int NKB = 512 / BK;
    gload(0);
    for (int kb = 0; kb < NKB; ++kb) {
        swrite();
        __syncthreads();
        if (kb < NKB - 1) gload(kb + 1);   // prefetch next step during compute
#pragma unroll
        for (int ks = 0; ks < BK / 16; ++ks) {
            const int pos = ks * 2 + hi8;
            short8v a0, a1;
            { const int r = wm * 64 + lane31;
              a0 = *(const short8v*)((char*)As + r * RB + ((pos ^ ((r >> 1) & SWM)) << 4)); }
            { const int r = wm * 64 + 32 + lane31;
              a1 = *(const short8v*)((char*)As + r * RB + ((pos ^ ((r >> 1) & SWM)) << 4)); }
            if constexpr (BN == 64) {
                short8v b0h;
                { const int r = wn * 32 + lane31;
                  b0h = *(const short8v*)((char*)Bs + r * RB + ((pos ^ ((r >> 1) & SWM)) << 4)); }
                acc00 = mfma3216(a0, b0h, acc00);
                acc10 = mfma3216(a1, b0h, acc10);
            } else {
                short8v b0h, b1h;
                { const int r = wn * 64 + lane31;
                  b0h = *(const short8v*)((char*)Bs + r * RB + ((pos ^ ((r >> 1) & SWM)) << 4)); }
                { const int r = wn * 64 + 32 + lane31;
                  b1h = *(const short8v*)((char*)Bs + r * RB + ((pos ^ ((r >> 1) & SWM)) << 4)); }
                acc00 = mfma3216(a0, b0h, acc00);
                acc01 = mfma3216(a0, b1h, acc01);
                acc10 = mfma3216(a1, b0h, acc10);
                acc11 = mfma3216(a1, b1h, acc11);
            }
        }
        __syncthreads();
    }

    // ---- epilogue
    const int nb = n0 + wn * (BN / 2) + lane31;
#pragma unroll
    for (int r = 0; r < 16; ++r) {
        const int row = (r & 3) + 8 * (r >> 2) + 4 * hi8;
        store_c<MODE>(outb, outf, m0 + wm * 64 + row,      nb, acc00[r] + bias[nb] * bscale);
        store_c<MODE>(outb, outf, m0 + wm * 64 + 32 + row, nb, acc10[r] + bias[nb] * bscale);
        if constexpr (BN == 128) {
            store_c<MODE>(outb, outf, m0 + wm * 64 + row,      nb + 32, acc01[r] + bias[nb + 32] * bscale);
            store_c<MODE>(outb, outf, m0 + wm * 64 + 32 + row, nb + 32, acc11[r] + bias[nb + 32] * bscale);
        }
    }
}

// qkv: BK=32 (r16 proven) + XCD-consolidation swizzle ONLY (isolating r17's
// bundle): linear dispatch puts the 4 blocks sharing an A-panel on 4
// different XCDs; remap (bijective) so they share one XCD's L2.
__global__ __launch_bounds__(256) void qkv_gemm(
    const float* __restrict__ q, const float* __restrict__ k, const float* __restrict__ v,
    const float* __restrict__ Wq, const float* __restrict__ Wk, const float* __restrict__ Wv,
    const float* __restrict__ bq, const float* __restrict__ bk, const float* __restrict__ bv,
    unsigned short* __restrict__ Qh, unsigned short* __restrict__ Kf,
    unsigned short* __restrict__ Vf)
{
    const int lin  = blockIdx.x + 4 * blockIdx.y;   // 0..127
    const int xcd  = lin & 7, slot = lin >> 3;      // slot 0..15
    const int bx   = slot & 3;                      // n-tile
    const int by   = xcd + 8 * (slot >> 2);         // m-tile: same-A blocks -> same XCD
    const int z = blockIdx.z;
    if (z == 0)      gemm_body<1, true, 128, 32>(q, Wq, bq, LOG2E, LOG2E, Qh, nullptr, bx, by);
    else if (z == 1) gemm_body<3, true, 128, 32>(k, Wk, bk, 1.0f,  1.0f,  Kf, nullptr, bx, by);
    else             gemm_body<4, true, 128, 32>(v, Wv, bv, 1.0f,  1.0f,  Vf, nullptr, bx, by);
}

__global__ __launch_bounds__(256) void out_gemm(
    const unsigned short* __restrict__ A, const float* __restrict__ Wo,
    const float* __restrict__ bias, float* __restrict__ out)
{
    gemm_body<0, false, 64, 64>(A, Wo, bias, 1.0f, 1.0f, nullptr, out,
                                blockIdx.x, blockIdx.y);
}

// ---------------------------------------------------------------------------
// MFMA two-pass attention — r12/r15/r16 VERBATIM (proven 47.5 µs form).
// 8 waves, 8-way key split, exp2, permlane repack, 4-partial lsum,
// two-stage LDS combine. 1024 blocks of 32 q-rows.
// ---------------------------------------------------------------------------
__global__ __launch_bounds__(512) void attn_kernel(
    const unsigned short* __restrict__ Qh, const unsigned short* __restrict__ Kf,
    const unsigned short* __restrict__ Vf, unsigned short* __restrict__ concat)
{
    __shared__ float lds_l[8][32];
    __shared__ float lds_out[4][32][64];   // 32 KB, two-stage combine

    const int bid = blockIdx.x;
    const int xcd = bid & 7;
    const int j   = bid >> 3;
    const int bh  = 2 * xcd + (j >> 6);
    const int qt  = j & 63;

    const int tid    = threadIdx.x;
    const int w      = tid >> 6;         // 0..7: key octant
    const int l      = tid & 63;
    const int lane31 = l & 31;
    const int hi     = l >> 5;

    const int q0 = qt * 32;
    const unsigned short* Qb = Qh + ((size_t)bh * T_ + q0) * DK_;

    // Q B-fragments: col = lane31 (query), k = d = c*16 + hi*8 + {0..7}
    short8v qf[4];
#pragma unroll
    for (int c = 0; c < 4; ++c)
        qf[c] = *(const short8v*)(Qb + (size_t)lane31 * DK_ + c * 16 + hi * 8);

    // fragment-major bases for this wave's 8 tiles (keys w*256 .. w*256+255)
    const unsigned short* Kw = Kf + ((size_t)bh * 64 + w * 8) * 2048 + hi * 256 + lane31 * 8;
    const unsigned short* Vw = Vf + ((size_t)bh * 64 + w * 8) * 2048 + hi * 256 + lane31 * 8;

    // ---- pass 1: denominators (exp2; 4 partial sums)
    float ls0 = 0.f, ls1 = 0.f, ls2 = 0.f, ls3 = 0.f;
    for (int kt = 0; kt < 8; ++kt) {
        const unsigned short* Kt = Kw + kt * 2048;
        short8v kf[4];
#pragma unroll
        for (int c = 0; c < 4; ++c)
            kf[c] = *(const short8v*)(Kt + c * 512);
        f32x16 acc = {};
        __builtin_amdgcn_s_setprio(1);
#pragma unroll
        for (int c = 0; c < 4; ++c)
            acc = mfma3216(kf[c], qf[c], acc);
        __builtin_amdgcn_s_setprio(0);
#pragma unroll
        for (int r = 0; r < 16; r += 4) {
            ls0 += __builtin_amdgcn_exp2f(acc[r + 0]);
            ls1 += __builtin_amdgcn_exp2f(acc[r + 1]);
            ls2 += __builtin_amdgcn_exp2f(acc[r + 2]);
            ls3 += __builtin_amdgcn_exp2f(acc[r + 3]);
        }
    }
    float lsum = (ls0 + ls1) + (ls2 + ls3);
    lsum += __shfl_xor(lsum, 32);
    if (l < 32) lds_l[w][l] = lsum;
    __syncthreads();
    float ltot = 0.f;
#pragma unroll
    for (int i = 0; i < 8; ++i) ltot += lds_l[i][lane31];
    const float thr = ltot * (1.0f / 2048.0f);   // e > thr  <=>  p > row mean (=1/T)
    const float inv = 1.0f / ltot;

    // ---- pass 2: masked PV (exp2, permlane repack)
    f32x16 o0 = {}, o1 = {};
    for (int kt = 0; kt < 8; ++kt) {
        const unsigned short* Kt = Kw + kt * 2048;
        short8v kf[4];
#pragma unroll
        for (int c = 0; c < 4; ++c)
            kf[c] = *(const short8v*)(Kt + c * 512);
        f32x16 acc = {};
        __builtin_amdgcn_s_setprio(1);
#pragma unroll
        for (int c = 0; c < 4; ++c)
            acc = mfma3216(kf[c], qf[c], acc);
        __builtin_amdgcn_s_setprio(0);

        float p[16];
#pragma unroll
        for (int r = 0; r < 16; ++r) {
            const float e = __builtin_amdgcn_exp2f(acc[r]);
            p[r] = (e > thr) ? e : 0.f;
        }

        // repack S^T -> PV A-frag via permlane32_swap
        short8v pa[2];
#pragma unroll
        for (int h = 0; h < 2; ++h) {
            unsigned a  = pk2(p[8 * h + 0], p[8 * h + 1]);
            unsigned b2 = pk2(p[8 * h + 2], p[8 * h + 3]);
            unsigned c2 = pk2(p[8 * h + 4], p[8 * h + 5]);
            unsigned d2 = pk2(p[8 * h + 6], p[8 * h + 7]);
            pl32swap(a, c2);
            pl32swap(b2, d2);
            union { unsigned w2[4]; short8v v8; } u;
            u.w2[0] = a; u.w2[1] = b2; u.w2[2] = c2; u.w2[3] = d2;
            pa[h] = u.v8;
        }

        const unsigned short* Vt_ = Vw + kt * 2048;
        short8v vf0 = *(const short8v*)(Vt_);
        short8v vf1 = *(const short8v*)(Vt_ + 512);
        short8v vf2 = *(const short8v*)(Vt_ + 1024);
        short8v vf3 = *(const short8v*)(Vt_ + 1536);
        __builtin_amdgcn_s_setprio(1);
        o0 = mfma3216(pa[0], vf0, o0);
        o1 = mfma3216(pa[0], vf1, o1);
        o0 = mfma3216(pa[1], vf2, o0);
        o1 = mfma3216(pa[1], vf3, o1);
        __builtin_amdgcn_s_setprio(0);
    }

    // ---- two-stage combine of 8 key-octants via 4 LDS buffers
    if (w >= 4) {
#pragma unroll
        for (int r = 0; r < 16; ++r) {
            const int row = (r & 3) + 8 * (r >> 2) + 4 * hi;
            lds_out[w - 4][row][lane31]      = o0[r];
            lds_out[w - 4][row][32 + lane31] = o1[r];
        }
    }
    __syncthreads();
    if (w < 4) {
#pragma unroll
        for (int r = 0; r < 16; ++r) {
            const int row = (r & 3) + 8 * (r >> 2) + 4 * hi;
            o0[r] += lds_out[w][row][lane31];
            o1[r] += lds_out[w][row][32 + lane31];
        }
    }
    __syncthreads();
    if (w >= 1 && w < 4) {
#pragma unroll
        for (int r = 0; r < 16; ++r) {
            const int row = (r & 3) + 8 * (r >> 2) + 4 * hi;
            lds_out[w - 1][row][lane31]      = o0[r];
            lds_out[w - 1][row][32 + lane31] = o1[r];
        }
    }
    __syncthreads();
    if (w == 0) {
        const int b = bh >> 3, h = bh & 7;
        unsigned short* Cb = concat + ((size_t)b * T_ + q0) * DOUT + h * DK_;
#pragma unroll
        for (int r = 0; r < 16; ++r) {
            const int row = (r & 3) + 8 * (r >> 2) + 4 * hi;
            const float iv = __shfl(inv, row);
            const float v0 = o0[r] + lds_out[0][row][lane31]
                           + lds_out[1][row][lane31] + lds_out[2][row][lane31];
            const float v1 = o1[r] + lds_out[0][row][32 + lane31]
                           + lds_out[1][row][32 + lane31] + lds_out[2][row][32 + lane31];
            Cb[(size_t)row * DOUT + lane31]      = bf16c(v0 * iv);
            Cb[(size_t)row * DOUT + 32 + lane31] = bf16c(v1 * iv);
        }
    }
}

// ---------------------------------------------------------------------------
extern "C" void kernel_launch(void* const* d_in, const int* in_sizes, int n_in,
                              void* d_out, int out_size, void* d_ws, size_t ws_size,
                              hipStream_t stream)
{
    const float* q  = (const float*)d_in[0];
    const float* k  = (const float*)d_in[1];
    const float* v  = (const float*)d_in[2];
    const float* Wq = (const float*)d_in[3];
    const float* bq = (const float*)d_in[4];
    const float* Wk = (const float*)d_in[5];
    const float* bk = (const float*)d_in[6];
    const float* Wv = (const float*)d_in[7];
    const float* bv = (const float*)d_in[8];
    const float* Wo = (const float*)d_in[9];
    const float* bo = (const float*)d_in[10];
    float* out = (float*)d_out;

    constexpr size_t M2 = 2097152;  // 2M elements
    unsigned short* ws     = (unsigned short*)d_ws;
    unsigned short* Qh     = ws;
    unsigned short* Kf     = ws + 1 * M2;
    unsigned short* Vf     = ws + 2 * M2;
    unsigned short* concat = ws + 3 * M2;

    qkv_gemm<<<dim3(4, 32, 3), 256, 0, stream>>>(q, k, v, Wq, Wk, Wv, bq, bk, bv, Qh, Kf, Vf);
    attn_kernel<<<dim3(1024), 512, 0, stream>>>(Qh, Kf, Vf, concat);
    out_gemm<<<dim3(8, 32), 256, 0, stream>>>(concat, Wo, bo, out);
}